// Round 2
// baseline (567.265 us; speedup 1.0000x reference)
//
#include <hip/hip_runtime.h>
#include <stdint.h>

#define CIN 64
#define COUT 128
#define BLOCK 256
#define WT_STRIDE 136   // 128 + 8 pad, in ushorts (272 B rows)

typedef __attribute__((ext_vector_type(8))) __bf16 bf16x8;
typedef __attribute__((ext_vector_type(8))) unsigned short ushort8;
typedef __attribute__((ext_vector_type(4))) float f32x4;

__device__ __forceinline__ unsigned short f2bf(float f) {
    // round-to-nearest-even fp32 -> bf16
    uint32_t u = __float_as_uint(f);
    u = (u + 0x7FFFu + ((u >> 16) & 1u)) >> 16;
    return (unsigned short)u;
}

// Build inverse map: for each input row i, record i+1 at inv[kz][out_ids[i]].
// At most one input per (output, tap) pair -> plain stores, no atomics needed.
__global__ void scatter_inv_kernel(const int* __restrict__ kz,
                                   const int* __restrict__ oid,
                                   int* __restrict__ inv0,
                                   int* __restrict__ inv1,
                                   int n) {
    int i = blockIdx.x * blockDim.x + threadIdx.x;
    if (i < n) {
        int o = oid[i];
        if (kz[i] == 0) inv0[o] = i + 1;
        else            inv1[o] = i + 1;
    }
}

// One wave == one 16-row output tile. No LDS staging of A, no per-tile
// barriers: feature fragments are gathered straight into MFMA B-operand
// layout (lane lrow,quad -> row lrow, floats (s&1)*32+quad*8..+8).
// MFMA operands are SWAPPED (W as A-operand, feat as B-operand) so each
// lane's accumulator holds 4 consecutive output columns of ONE row ->
// float4 stores + broadcast float4 BN reads.
__launch_bounds__(BLOCK, 4)
__global__ void spconv_bn_relu_kernel(const float* __restrict__ feat,
                                      const float* __restrict__ W,
                                      const float* __restrict__ gamma,
                                      const float* __restrict__ beta,
                                      const float* __restrict__ rmean,
                                      const float* __restrict__ rvar,
                                      const int* __restrict__ inv0,
                                      const int* __restrict__ inv1,
                                      const int* __restrict__ n_out_p,
                                      float* __restrict__ out,
                                      int N, int num_wtiles) {
    __shared__ unsigned short lds_wT[COUT * WT_STRIDE];      // 34816 B, WcatT[n][k] bf16
    __shared__ __align__(16) float lds_scale[COUT];
    __shared__ __align__(16) float lds_bias[COUT];

    const int tid = threadIdx.x;
    const int nout = *n_out_p;

    // ---- phase 0 (once per block): Wcat -> LDS, transposed, bf16 ----
    // W global layout: [tap][cin][cout] flat = (tap*64+cin)*128 + cout = k*128 + n
    const float4* W4 = (const float4*)W;
    #pragma unroll
    for (int u = 0; u < 16; ++u) {
        int flat4 = u * BLOCK + tid;   // 0..4095 float4s
        int n4 = flat4 & 31;           // float4 index within a 128-cout row
        int k  = flat4 >> 5;           // 0..127 = tap*64+cin
        float4 v = W4[flat4];
        int nb = n4 * 4;
        lds_wT[(nb + 0) * WT_STRIDE + k] = f2bf(v.x);
        lds_wT[(nb + 1) * WT_STRIDE + k] = f2bf(v.y);
        lds_wT[(nb + 2) * WT_STRIDE + k] = f2bf(v.z);
        lds_wT[(nb + 3) * WT_STRIDE + k] = f2bf(v.w);
    }
    if (tid < COUT) {
        float s = gamma[tid] * rsqrtf(rvar[tid] + 1e-5f);
        lds_scale[tid] = s;
        lds_bias[tid]  = fmaf(-rmean[tid], s, beta[tid]);
    }
    __syncthreads();   // only barrier in the kernel

    const float4* feat4 = (const float4*)feat;
    const int wave = tid >> 6;
    const int lane = tid & 63;
    const int lrow = lane & 15;
    const int quad = lane >> 4;

    const int gwave   = blockIdx.x * (BLOCK / 64) + wave;
    const int wstride = gridDim.x * (BLOCK / 64);

    // prologue: inv indices for the first tile
    int i0 = 0, i1 = 0;
    if (gwave < num_wtiles) {
        int row = gwave * 16 + lrow;
        if (row < N) { i0 = inv0[row]; i1 = inv1[row]; }
    }

    for (int wt = gwave; wt < num_wtiles; wt += wstride) {
        const int row = wt * 16 + lrow;

        // ---- gather raw fp32 fragments (8 outstanding dwordx4 per lane) ----
        float4 ra[4], rb[4];
        #pragma unroll
        for (int s = 0; s < 4; ++s) {
            int idx = (s < 2) ? i0 : i1;
            ra[s] = make_float4(0.f, 0.f, 0.f, 0.f);
            rb[s] = make_float4(0.f, 0.f, 0.f, 0.f);
            if (idx > 0) {
                const float4* p = feat4 + (size_t)(idx - 1) * 16 + (s & 1) * 8 + quad * 2;
                ra[s] = p[0];
                rb[s] = p[1];
            }
        }

        // prefetch next tile's inv indices (breaks the inv->feat serial chain)
        int nwt = wt + wstride;
        int p0 = 0, p1 = 0;
        if (nwt < num_wtiles) {
            int nr = nwt * 16 + lrow;
            if (nr < N) { p0 = inv0[nr]; p1 = inv1[nr]; }
        }

        // ---- convert to bf16 fragments (MFMA B-operand layout) ----
        bf16x8 afrag[4];
        #pragma unroll
        for (int s = 0; s < 4; ++s) {
            ushort8 u;
            u[0] = f2bf(ra[s].x); u[1] = f2bf(ra[s].y);
            u[2] = f2bf(ra[s].z); u[3] = f2bf(ra[s].w);
            u[4] = f2bf(rb[s].x); u[5] = f2bf(rb[s].y);
            u[6] = f2bf(rb[s].z); u[7] = f2bf(rb[s].w);
            afrag[s] = __builtin_bit_cast(bf16x8, u);
        }

        // ---- MFMA (swapped operands) + fused BN/ReLU epilogue ----
        #pragma unroll
        for (int c = 0; c < 8; ++c) {
            const unsigned short* bbase = &lds_wT[(c * 16 + lrow) * WT_STRIDE + quad * 8];
            f32x4 acc = {0.f, 0.f, 0.f, 0.f};
            #pragma unroll
            for (int s = 0; s < 4; ++s) {
                bf16x8 wfrag = __builtin_bit_cast(bf16x8, *(const ushort8*)(bbase + s * 32));
                acc = __builtin_amdgcn_mfma_f32_16x16x32_bf16(wfrag, afrag[s], acc, 0, 0, 0);
            }
            // lane holds out[row][c*16 + quad*4 .. +3]
            if (row < N) {
                const int col = c * 16 + quad * 4;
                float4 o4 = make_float4(0.f, 0.f, 0.f, 0.f);
                if (row < nout) {
                    f32x4 sc = *(const f32x4*)&lds_scale[col];
                    f32x4 bi = *(const f32x4*)&lds_bias[col];
                    o4.x = fmaxf(fmaf(acc[0], sc[0], bi[0]), 0.f);
                    o4.y = fmaxf(fmaf(acc[1], sc[1], bi[1]), 0.f);
                    o4.z = fmaxf(fmaf(acc[2], sc[2], bi[2]), 0.f);
                    o4.w = fmaxf(fmaf(acc[3], sc[3], bi[3]), 0.f);
                }
                *(float4*)&out[(size_t)row * COUT + col] = o4;
            }
        }

        i0 = p0; i1 = p1;
    }
}

extern "C" void kernel_launch(void* const* d_in, const int* in_sizes, int n_in,
                              void* d_out, int out_size, void* d_ws, size_t ws_size,
                              hipStream_t stream) {
    const float* feat  = (const float*)d_in[0];
    const float* W     = (const float*)d_in[1];
    const float* gamma = (const float*)d_in[2];
    const float* beta  = (const float*)d_in[3];
    const float* rmean = (const float*)d_in[4];
    const float* rvar  = (const float*)d_in[5];
    const int*   kz    = (const int*)d_in[6];
    const int*   oid   = (const int*)d_in[7];
    const int*   noutp = (const int*)d_in[8];
    float* out = (float*)d_out;

    const int N = in_sizes[6];   // 600000

    int* inv0 = (int*)d_ws;
    int* inv1 = inv0 + N;

    // inv maps: 0 = no contributor (ws is re-poisoned each call, so always clear)
    hipMemsetAsync(d_ws, 0, (size_t)2 * N * sizeof(int), stream);

    int sb = (N + 255) / 256;
    scatter_inv_kernel<<<sb, 256, 0, stream>>>(kz, oid, inv0, inv1, N);

    int num_wtiles = (N + 15) / 16;                       // 37500 wave-tiles
    int nblocks = (num_wtiles + 3) / 4;
    int grid = nblocks < 1024 ? nblocks : 1024;           // 4 blocks/CU co-resident
    spconv_bn_relu_kernel<<<grid, BLOCK, 0, stream>>>(
        feat, W, gamma, beta, rmean, rvar, inv0, inv1, noutp, out, N, num_wtiles);
}

// Round 3
// 562.681 us; speedup vs baseline: 1.0081x; 1.0081x over previous
//
#include <hip/hip_runtime.h>
#include <stdint.h>

#define CIN 64
#define COUT 128
#define BLOCK 256
#define WPB 4                 // waves per block
#define WT_STRIDE 136         // ushorts per W^T row (272 B = 4-bank rotate)
#define SEG_STRIDE 144        // bytes per staged (tap,row) segment (4-bank rotate, 16B-aligned)
// per-wave stage: 32 segs * 144 B = 4608 B; block total LDS = 34816 + 18432 + 1024 = 54272 B
// -> 3 blocks/CU (162816 <= 163840), 12 waves/CU

typedef __attribute__((ext_vector_type(8))) __bf16 bf16x8;
typedef __attribute__((ext_vector_type(8))) unsigned short ushort8;
typedef __attribute__((ext_vector_type(4))) float f32x4;

__device__ __forceinline__ unsigned short f2bf(float f) {
    // round-to-nearest-even fp32 -> bf16
    uint32_t u = __float_as_uint(f);
    u = (u + 0x7FFFu + ((u >> 16) & 1u)) >> 16;
    return (unsigned short)u;
}

// Build inverse map: for each input row i, record i+1 at inv[kz][out_ids[i]].
// At most one input per (output, tap) pair -> plain stores, no atomics needed.
__global__ void scatter_inv_kernel(const int* __restrict__ kz,
                                   const int* __restrict__ oid,
                                   int* __restrict__ inv0,
                                   int* __restrict__ inv1,
                                   int n) {
    int i = blockIdx.x * blockDim.x + threadIdx.x;
    if (i < n) {
        int o = oid[i];
        if (kz[i] == 0) inv0[o] = i + 1;
        else            inv1[o] = i + 1;
    }
}

// One wave == one 16-row output tile, grid-stride, NO inter-wave barriers in
// the loop. Feature rows are gathered with COALESCED 256-B-contiguous reads
// (8 lanes x 32 B per row), converted to bf16, bounced through a wave-private
// LDS buffer (same-wave DS ops are in-order -> lgkmcnt only, no barrier),
// then read back in MFMA fragment layout. Next tile's gathers are issued
// before the MFMA phase (async-split) so HBM latency hides under compute.
// MFMA operands swapped (W^T as A) -> lane holds 4 consecutive output cols
// of one row -> float4 stores + broadcast float4 BN reads.
__launch_bounds__(BLOCK, 3)
__global__ void spconv_bn_relu_kernel(const float* __restrict__ feat,
                                      const float* __restrict__ W,
                                      const float* __restrict__ gamma,
                                      const float* __restrict__ beta,
                                      const float* __restrict__ rmean,
                                      const float* __restrict__ rvar,
                                      const int* __restrict__ inv0,
                                      const int* __restrict__ inv1,
                                      const int* __restrict__ n_out_p,
                                      float* __restrict__ out,
                                      int N, int num_wtiles) {
    __shared__ unsigned short lds_wT[COUT * WT_STRIDE];                      // 34816 B
    __shared__ __align__(16) unsigned char lds_stage[WPB * 32 * SEG_STRIDE]; // 18432 B
    __shared__ __align__(16) float lds_scale[COUT];
    __shared__ __align__(16) float lds_bias[COUT];

    const int tid = threadIdx.x;
    const int nout = *n_out_p;

    // ---- phase 0 (once per block): Wcat -> LDS, transposed, bf16 ----
    // W global layout: [tap][cin][cout] flat = (tap*64+cin)*128 + cout = k*128 + n
    const float4* W4 = (const float4*)W;
    #pragma unroll
    for (int u = 0; u < 16; ++u) {
        int flat4 = u * BLOCK + tid;   // 0..4095 float4s
        int n4 = flat4 & 31;           // float4 index within a 128-cout row
        int k  = flat4 >> 5;           // 0..127 = tap*64+cin
        float4 v = W4[flat4];
        int nb = n4 * 4;
        lds_wT[(nb + 0) * WT_STRIDE + k] = f2bf(v.x);
        lds_wT[(nb + 1) * WT_STRIDE + k] = f2bf(v.y);
        lds_wT[(nb + 2) * WT_STRIDE + k] = f2bf(v.z);
        lds_wT[(nb + 3) * WT_STRIDE + k] = f2bf(v.w);
    }
    if (tid < COUT) {
        float s = gamma[tid] * rsqrtf(rvar[tid] + 1e-5f);
        lds_scale[tid] = s;
        lds_bias[tid]  = fmaf(-rmean[tid], s, beta[tid]);
    }
    __syncthreads();   // only barrier in the kernel

    const float4* feat4 = (const float4*)feat;
    const int wave   = tid >> 6;
    const int lane   = tid & 63;
    const int lrow   = lane & 15;
    const int quad   = lane >> 4;
    const int lseg   = lane >> 3;   // 0..7: which segment within a load round
    const int lchunk = lane & 7;    // 0..7: 32-B chunk within the 256-B row

    unsigned char* stg = lds_stage + wave * (32 * SEG_STRIDE);

    const int gwave   = blockIdx.x * WPB + wave;
    const int wstride = gridDim.x * WPB;

    // inv indices for the first tile (per-lane, lrow-indexed)
    int i0 = 0, i1 = 0;
    if (gwave < num_wtiles) {
        int row = gwave * 16 + lrow;
        if (row < N) { i0 = inv0[row]; i1 = inv1[row]; }
    }

    // prologue: issue tile-0 gathers (coalesced: 8 lanes cover one row's 256 B)
    float4 ga[4], gb[4];
    #pragma unroll
    for (int r = 0; r < 4; ++r) {
        int seg = r * 8 + lseg;             // 0..31 = tap*16 + row
        int rs  = seg & 15;
        int idx = (seg & 16) ? __shfl(i1, rs, 64) : __shfl(i0, rs, 64);
        ga[r] = make_float4(0.f, 0.f, 0.f, 0.f);
        gb[r] = ga[r];
        if (idx > 0) {
            const float4* p = feat4 + (size_t)(idx - 1) * 16 + lchunk * 2;
            ga[r] = p[0];
            gb[r] = p[1];
        }
    }

    for (int wt = gwave; wt < num_wtiles; wt += wstride) {
        const int row = wt * 16 + lrow;

        // prefetch next tile's inv indices
        int nwt = wt + wstride;
        int p0 = 0, p1 = 0;
        if (nwt < num_wtiles) {
            int nr = nwt * 16 + lrow;
            if (nr < N) { p0 = inv0[nr]; p1 = inv1[nr]; }
        }

        // ---- stage current tile to wave-private LDS (bf16) ----
        #pragma unroll
        for (int r = 0; r < 4; ++r) {
            int seg = r * 8 + lseg;
            ushort8 u;
            u[0] = f2bf(ga[r].x); u[1] = f2bf(ga[r].y);
            u[2] = f2bf(ga[r].z); u[3] = f2bf(ga[r].w);
            u[4] = f2bf(gb[r].x); u[5] = f2bf(gb[r].y);
            u[6] = f2bf(gb[r].z); u[7] = f2bf(gb[r].w);
            *(ushort8*)(stg + seg * SEG_STRIDE + lchunk * 16) = u;
        }

        // ---- issue NEXT tile's gathers now: latency hides under MFMA ----
        float4 na[4], nb[4];
        #pragma unroll
        for (int r = 0; r < 4; ++r) {
            int seg = r * 8 + lseg;
            int rs  = seg & 15;
            int idx = (seg & 16) ? __shfl(p1, rs, 64) : __shfl(p0, rs, 64);
            na[r] = make_float4(0.f, 0.f, 0.f, 0.f);
            nb[r] = na[r];
            if (idx > 0) {
                const float4* p = feat4 + (size_t)(idx - 1) * 16 + lchunk * 2;
                na[r] = p[0];
                nb[r] = p[1];
            }
        }

        // ---- fragments from LDS (same-wave in-order DS: no barrier) ----
        bf16x8 afrag[4];
        #pragma unroll
        for (int s = 0; s < 4; ++s) {
            int seg = (s >> 1) * 16 + lrow;   // tap = s>>1, row = lrow
            afrag[s] = __builtin_bit_cast(bf16x8,
                *(const ushort8*)(stg + seg * SEG_STRIDE + (s & 1) * 64 + quad * 16));
        }

        // ---- MFMA (swapped operands) + fused BN/ReLU epilogue ----
        #pragma unroll
        for (int c = 0; c < 8; ++c) {
            const unsigned short* bbase = &lds_wT[(c * 16 + lrow) * WT_STRIDE + quad * 8];
            f32x4 acc = {0.f, 0.f, 0.f, 0.f};
            #pragma unroll
            for (int s = 0; s < 4; ++s) {
                bf16x8 wfrag = __builtin_bit_cast(bf16x8, *(const ushort8*)(bbase + s * 32));
                acc = __builtin_amdgcn_mfma_f32_16x16x32_bf16(wfrag, afrag[s], acc, 0, 0, 0);
            }
            // lane holds out[row][c*16 + quad*4 .. +3]
            if (row < N) {
                const int col = c * 16 + quad * 4;
                float4 o4 = make_float4(0.f, 0.f, 0.f, 0.f);
                if (row < nout) {
                    f32x4 sc = *(const f32x4*)&lds_scale[col];
                    f32x4 bi = *(const f32x4*)&lds_bias[col];
                    o4.x = fmaxf(fmaf(acc[0], sc[0], bi[0]), 0.f);
                    o4.y = fmaxf(fmaf(acc[1], sc[1], bi[1]), 0.f);
                    o4.z = fmaxf(fmaf(acc[2], sc[2], bi[2]), 0.f);
                    o4.w = fmaxf(fmaf(acc[3], sc[3], bi[3]), 0.f);
                }
                *(float4*)&out[(size_t)row * COUT + col] = o4;
            }
        }

        // rotate pipeline state
        i0 = p0; i1 = p1;
        #pragma unroll
        for (int r = 0; r < 4; ++r) { ga[r] = na[r]; gb[r] = nb[r]; }
    }
}

extern "C" void kernel_launch(void* const* d_in, const int* in_sizes, int n_in,
                              void* d_out, int out_size, void* d_ws, size_t ws_size,
                              hipStream_t stream) {
    const float* feat  = (const float*)d_in[0];
    const float* W     = (const float*)d_in[1];
    const float* gamma = (const float*)d_in[2];
    const float* beta  = (const float*)d_in[3];
    const float* rmean = (const float*)d_in[4];
    const float* rvar  = (const float*)d_in[5];
    const int*   kz    = (const int*)d_in[6];
    const int*   oid   = (const int*)d_in[7];
    const int*   noutp = (const int*)d_in[8];
    float* out = (float*)d_out;

    const int N = in_sizes[6];   // 600000

    int* inv0 = (int*)d_ws;
    int* inv1 = inv0 + N;

    // inv maps: 0 = no contributor (ws is re-poisoned each call, so always clear)
    hipMemsetAsync(d_ws, 0, (size_t)2 * N * sizeof(int), stream);

    int sb = (N + 255) / 256;
    scatter_inv_kernel<<<sb, 256, 0, stream>>>(kz, oid, inv0, inv1, N);

    int num_wtiles = (N + 15) / 16;                       // 37500 wave-tiles
    int nblocks = (num_wtiles + WPB - 1) / WPB;
    int grid = nblocks < 768 ? nblocks : 768;             // 3 blocks/CU co-resident
    spconv_bn_relu_kernel<<<grid, BLOCK, 0, stream>>>(
        feat, W, gamma, beta, rmean, rvar, inv0, inv1, noutp, out, N, num_wtiles);
}